// Round 13
// baseline (47.004 us; speedup 1.0000x reference)
//
#include <hip/hip_runtime.h>
#include <cmath>

#define BN 8192
#define DIM 128
#define MARGIN_F 0.3f
#define NRB 64                 // 128-row blocks
#define NPAIR 32               // row-block pairs (p, 63-p), 65 tiles each
#define NCHUNK 16              // column chunks per pair -> grid (32,16)=512 blocks
#define NRSLOT (NCHUNK * 2)    // row-side partial slots (chunk x wc)
#define IMAX 0x7FFFFFFF
#define IMIN 0x80000000

typedef __attribute__((ext_vector_type(4))) int i32x4;

__device__ __forceinline__ int imin3(int a, int b, int c) { return min(a, min(b, c)); }
__device__ __forceinline__ int imax3(int a, int b, int c) { return max(a, max(b, c)); }

// ---------------- K1: fp32 row norms -> sqv + k-major i8 quantized copy ----------------
// Also LP: packed column-label table (LP[cb*16+lrow] = label bytes of cols
// cb*64 + {0,16,32,48} + lrow; 128 groups, 8 KB, L2-resident).
__global__ __launch_bounds__(256) void norm_cvt_k(
    const float* __restrict__ emb, const int* __restrict__ lab,
    float* __restrict__ sqv, unsigned short* __restrict__ EnQ16,
    unsigned* __restrict__ LP)
{
  int gt = blockIdx.x * blockDim.x + threadIdx.x;
  if (gt < 2048) {
    int base = (gt >> 4) * 64 + (gt & 15);
    LP[gt] = (unsigned)(lab[base] & 255) | ((unsigned)(lab[base + 16] & 255) << 8) |
             ((unsigned)(lab[base + 32] & 255) << 16) | ((unsigned)(lab[base + 48] & 255) << 24);
  }

  int w = gt >> 6;  // one wave per row
  int lane = threadIdx.x & 63;
  if (w >= BN) return;
  float2 v = *reinterpret_cast<const float2*>(&emb[w * DIM + lane * 2]);
  float s = v.x * v.x + v.y * v.y;
  #pragma unroll
  for (int off = 32; off > 0; off >>= 1) s += __shfl_xor(s, off);
  float iv = 1.0f / fmaxf(sqrtf(s), 1e-12f);
  if (lane == 0) sqv[w] = s * iv * iv;
  int q0 = (int)rintf(127.0f * v.x * iv);
  int q1 = (int)rintf(127.0f * v.y * iv);
  unsigned short us = (unsigned short)((q0 & 255) | ((q1 & 255) << 8));
  int g = lane >> 3;                                  // k = 2*lane -> chunk g = lane/8
  EnQ16[(g * BN + w) * 8 + (lane & 7)] = us;
}

// ---------------- K2: balanced-strip triangular gram + two-sided mining ----------------
// r12 lesson: one tile/block re-ran the prologue 4x more than r8 and lost the
// triangle's gains. Fix: pair (p, 63-p) owns exactly 65 tiles; grid (32,16) = 512
// blocks x ~4 tiles. A-frags/labels load once per SEGMENT (<=2x per block); row
// partials accumulate in registers across the chunk -> slot (y,wc) (sentinel-flush
// guarantees all 32 slots written). Col-side: per-tile LDS wr-combine -> slot R of
// col-block C (each (slot,row) written exactly once; finalize reads slots < X only).
__global__ __launch_bounds__(256, 2) void tri_strip_mine_k(
    const char* __restrict__ EnQ, const int* __restrict__ lab,
    const unsigned* __restrict__ LP,
    int* __restrict__ rp, int* __restrict__ rn,
    int* __restrict__ cp, int* __restrict__ cn)
{
  __shared__ int sCP[2][128], sCN[2][128];

  const int tid = threadIdx.x;
  const int w = tid >> 6, l = tid & 63;
  const int wr = w >> 1, wc = w & 1;
  const int lrow = l & 15, lkg = l >> 4;

  const int p = blockIdx.x, y = blockIdx.y;
  const int rbB = 63 - p, lenA = 64 - p;      // segment A: (p, p..63); B: (63-p, 63-p..63)
  const int start = (y * 65) >> 4;
  const int end   = ((y + 1) * 65) >> 4;
  const int rslot = y * 2 + wc;

  i32x4 a[4][2];
  int rlv[4][4];
  int ap[4][4], an[4][4];
  const i32x4 zf = {0, 0, 0, 0};

  auto resetAcc = [&]() {
    #pragma unroll
    for (int mi = 0; mi < 4; ++mi)
      #pragma unroll
      for (int r = 0; r < 4; ++r) { ap[mi][r] = IMAX; an[mi][r] = IMIN; }
  };
  auto loadRB = [&](int rb) {
    const int rowBase = rb * 128 + wr * 64;
    #pragma unroll
    for (int mi = 0; mi < 4; ++mi)
      #pragma unroll
      for (int kk = 0; kk < 2; ++kk)
        a[mi][kk] = *reinterpret_cast<const i32x4*>(
            EnQ + (((size_t)((kk << 2) + lkg) * BN + rowBase + mi * 16 + lrow) << 4));
    #pragma unroll
    for (int mi = 0; mi < 4; ++mi) {
      int rb8 = rowBase + mi * 16 + lkg * 4;
      #pragma unroll
      for (int r = 0; r < 4; ++r) rlv[mi][r] = lab[rb8 + r] & 255;
    }
    resetAcc();
  };
  auto flushRB = [&](int rb) {   // butterfly over the 16 lrow lanes, store slot rslot
    #pragma unroll
    for (int mi = 0; mi < 4; ++mi)
      #pragma unroll
      for (int r = 0; r < 4; ++r) {
        int pp = ap[mi][r], nn = an[mi][r];
        #pragma unroll
        for (int off = 1; off < 16; off <<= 1) {
          pp = min(pp, __shfl_xor(pp, off));
          nn = max(nn, __shfl_xor(nn, off));
        }
        if (lrow == 0) {
          int rg = rb * 128 + wr * 64 + mi * 16 + lkg * 4 + r;
          rp[(size_t)rslot * BN + rg] = pp;
          rn[(size_t)rslot * BN + rg] = nn;
        }
      }
  };

  auto mineRow = [&](const i32x4 (&A)[4][2], int la, int lb) {
    #pragma unroll
    for (int mi = 0; mi < 4; ++mi)
      #pragma unroll
      for (int r = 0; r < 4; ++r) {
        int d0 = A[mi][0][r], d1 = A[mi][1][r];
        bool s0 = (rlv[mi][r] == la), s1 = (rlv[mi][r] == lb);
        int p0 = s0 ? d0 : IMAX, p1 = s1 ? d1 : IMAX;
        int q0 = s0 ? IMIN : d0, q1 = s1 ? IMIN : d1;
        ap[mi][r] = imin3(ap[mi][r], p0, p1);
        an[mi][r] = imax3(an[mi][r], q0, q1);
      }
  };
  auto mineRowCol = [&](const i32x4 (&A)[4][2], int la, int lb,
                        int& cmA, int& cxA, int& cmB, int& cxB) {
    #pragma unroll
    for (int mi = 0; mi < 4; ++mi)
      #pragma unroll
      for (int r = 0; r < 4; ++r) {
        int d0 = A[mi][0][r], d1 = A[mi][1][r];
        bool s0 = (rlv[mi][r] == la), s1 = (rlv[mi][r] == lb);
        int p0 = s0 ? d0 : IMAX, p1 = s1 ? d1 : IMAX;
        int q0 = s0 ? IMIN : d0, q1 = s1 ? IMIN : d1;
        ap[mi][r] = imin3(ap[mi][r], p0, p1);
        an[mi][r] = imax3(an[mi][r], q0, q1);
        cmA = min(cmA, p0); cxA = max(cxA, q0);
        cmB = min(cmB, p1); cxB = max(cxB, q1);
      }
  };
  auto mineDiag = [&](const i32x4 (&A)[4][2], int la, int lb, int c0, int c1) {
    #pragma unroll
    for (int mi = 0; mi < 4; ++mi)
      #pragma unroll
      for (int r = 0; r < 4; ++r) {
        int rloc = mi * 16 + lkg * 4 + r;
        int d0 = A[mi][0][r], d1 = A[mi][1][r];
        bool s0 = (rlv[mi][r] == la), s1 = (rlv[mi][r] == lb);
        bool e0 = (rloc == c0), e1 = (rloc == c1);
        int p0 = (s0 && !e0) ? d0 : IMAX, p1 = (s1 && !e1) ? d1 : IMAX;
        int q0 = s0 ? IMIN : d0, q1 = s1 ? IMIN : d1;
        ap[mi][r] = imin3(ap[mi][r], p0, p1);
        an[mi][r] = imax3(an[mi][r], q0, q1);
      }
  };

  int curRB = -1;
  bool doneA = false, doneB = false;

  #pragma unroll 1
  for (int i = start; i < end; ++i) {
    int R, C;
    if (i < lenA) { R = p;   C = p + i; }
    else          { R = rbB; C = rbB + (i - lenA); }

    if (R != curRB) {                       // block-uniform branch
      if (curRB == p) { flushRB(p); doneA = true; }
      loadRB(R);
      curRB = R;
    }

    const int colBase = C * 128 + wc * 64;
    const bool diagBlk = (R == C);
    const bool diagW = diagBlk && (wr == wc);

    const unsigned LPv = LP[(C * 2 + wc) * 16 + lrow];
    const int l0 = (int)(LPv & 255u),         l1 = (int)((LPv >> 8) & 255u);
    const int l2 = (int)((LPv >> 16) & 255u), l3 = (int)(LPv >> 24);

    const char* bp0 = EnQ + (((size_t)lkg * BN + colBase + lrow) << 4);
    const char* bp1 = bp0 + ((size_t)BN << 6);
    i32x4 b0[2][2], b1[2][2];
    #pragma unroll
    for (int n = 0; n < 2; ++n) {
      b0[0][n] = *reinterpret_cast<const i32x4*>(bp0 + n * 256);
      b0[1][n] = *reinterpret_cast<const i32x4*>(bp1 + n * 256);
      b1[0][n] = *reinterpret_cast<const i32x4*>(bp0 + (2 + n) * 256);
      b1[1][n] = *reinterpret_cast<const i32x4*>(bp1 + (2 + n) * 256);
    }

    i32x4 accA[4][2], accB[4][2];
    #pragma unroll
    for (int mi = 0; mi < 4; ++mi)
      #pragma unroll
      for (int n = 0; n < 2; ++n)
        accA[mi][n] = __builtin_amdgcn_mfma_i32_16x16x64_i8(a[mi][0], b0[0][n], zf, 0, 0, 0);
    #pragma unroll
    for (int mi = 0; mi < 4; ++mi)
      #pragma unroll
      for (int n = 0; n < 2; ++n)
        accA[mi][n] = __builtin_amdgcn_mfma_i32_16x16x64_i8(a[mi][1], b0[1][n], accA[mi][n], 0, 0, 0);
    #pragma unroll
    for (int mi = 0; mi < 4; ++mi)
      #pragma unroll
      for (int n = 0; n < 2; ++n)
        accB[mi][n] = __builtin_amdgcn_mfma_i32_16x16x64_i8(a[mi][0], b1[0][n], zf, 0, 0, 0);
    #pragma unroll
    for (int mi = 0; mi < 4; ++mi)
      #pragma unroll
      for (int n = 0; n < 2; ++n)
        accB[mi][n] = __builtin_amdgcn_mfma_i32_16x16x64_i8(a[mi][1], b1[1][n], accB[mi][n], 0, 0, 0);

    int cmin[4], cmax[4];
    #pragma unroll
    for (int n = 0; n < 4; ++n) { cmin[n] = IMAX; cmax[n] = IMIN; }

    if (diagW) {
      mineDiag(accA, l0, l1, lrow, 16 + lrow);
      mineDiag(accB, l2, l3, 32 + lrow, 48 + lrow);
    } else if (!diagBlk) {
      mineRowCol(accA, l0, l1, cmin[0], cmax[0], cmin[1], cmax[1]);
      mineRowCol(accB, l2, l3, cmin[2], cmax[2], cmin[3], cmax[3]);
    } else {   // R==C block, off-diagonal wave tile
      mineRow(accA, l0, l1);
      mineRow(accB, l2, l3);
    }

    if (!diagBlk) {   // col-side: lkg-reduce, LDS wr-combine, store slot R
      #pragma unroll
      for (int n = 0; n < 4; ++n) {
        int cm = cmin[n], cx = cmax[n];
        cm = min(cm, __shfl_xor(cm, 16)); cm = min(cm, __shfl_xor(cm, 32));
        cx = max(cx, __shfl_xor(cx, 16)); cx = max(cx, __shfl_xor(cx, 32));
        if (lkg == 0) {
          int cl = wc * 64 + n * 16 + lrow;
          sCP[wr][cl] = cm; sCN[wr][cl] = cx;
        }
      }
      __syncthreads();
      if (tid < 128) {
        int pp = min(sCP[0][tid], sCP[1][tid]);
        int nn = max(sCN[0][tid], sCN[1][tid]);
        cp[(size_t)R * BN + C * 128 + tid] = pp;
        cn[(size_t)R * BN + C * 128 + tid] = nn;
      }
      __syncthreads();   // protect sCP reuse by the next tile
    }
  }

  if (curRB == p)        { flushRB(p);   doneA = true; }
  else if (curRB == rbB) { flushRB(rbB); doneB = true; }
  if (!doneA) { resetAcc(); flushRB(p);   }   // sentinel slots keep coverage total
  if (!doneB) { resetAcc(); flushRB(rbB); }
}

// ---------------- K3a: per-row combine: 32 row slots + X col slots; 64 blocks ----------------
__global__ __launch_bounds__(256) void finalize_a_k(
    const int* __restrict__ rp, const int* __restrict__ rn,
    const int* __restrict__ cp, const int* __restrict__ cn,
    const float* __restrict__ sqv,
    float* __restrict__ blk_sum, float* __restrict__ blk_cnt)
{
  __shared__ int sP[128], sN[128];
  __shared__ float ssum[4], scnt[4];
  const int X = blockIdx.x;
  const int tid = threadIdx.x;
  const int t = tid & 127, h = tid >> 7;     // h=0: row slots; h=1: col slots (<X)
  const int r = X * 128 + t;

  int apt = IMAX, ant = IMIN;
  if (h == 0) {
    #pragma unroll 8
    for (int s = 0; s < NRSLOT; ++s) {
      apt = min(apt, rp[(size_t)s * BN + r]);
      ant = max(ant, rn[(size_t)s * BN + r]);
    }
  } else {
    for (int s = 0; s < X; ++s) {
      apt = min(apt, cp[(size_t)s * BN + r]);
      ant = max(ant, cn[(size_t)s * BN + r]);
    }
  }
  if (h) { sP[t] = apt; sN[t] = ant; }
  __syncthreads();

  float sum = 0.f, cnt = 0.f;
  if (!h) {
    apt = min(apt, sP[t]); ant = max(ant, sN[t]);
    if (apt != IMAX && ant != IMIN) {
      const float sc = 2.0f / (127.0f * 127.0f);
      float rs1 = sqv[r] + 1.0f;
      float dap = sqrtf(fmaxf(fmaf(-sc, (float)apt, rs1), 0.f));
      float dan = sqrtf(fmaxf(fmaf(-sc, (float)ant, rs1), 0.f));
      sum = fmaxf(dap - dan + MARGIN_F, 0.f);
      cnt = 1.f;
    }
  }
  #pragma unroll
  for (int off = 32; off > 0; off >>= 1) {
    sum += __shfl_xor(sum, off);
    cnt += __shfl_xor(cnt, off);
  }
  int wv = tid >> 6;
  if ((tid & 63) == 0) { ssum[wv] = sum; scnt[wv] = cnt; }
  __syncthreads();
  if (tid == 0) {
    blk_sum[blockIdx.x] = ssum[0] + ssum[1] + ssum[2] + ssum[3];
    blk_cnt[blockIdx.x] = scnt[0] + scnt[1] + scnt[2] + scnt[3];
  }
}

// ---------------- K3b: final scalar over 64 block results ----------------
__global__ __launch_bounds__(64) void finalize_b_k(
    const float* __restrict__ blk_sum, const float* __restrict__ blk_cnt,
    float* __restrict__ out)
{
  int l = threadIdx.x;
  float s = blk_sum[l], c = blk_cnt[l];
  #pragma unroll
  for (int off = 32; off > 0; off >>= 1) {
    s += __shfl_xor(s, off);
    c += __shfl_xor(c, off);
  }
  if (l == 0) out[0] = (c > 0.f) ? (s / c) : 0.f;
}

extern "C" void kernel_launch(void* const* d_in, const int* in_sizes, int n_in,
                              void* d_out, int out_size, void* d_ws, size_t ws_size,
                              hipStream_t stream)
{
  const float* emb = (const float*)d_in[0];
  const int*   lab = (const int*)d_in[1];
  float* out = (float*)d_out;
  float* ws  = (float*)d_ws;

  float*    sqv     = ws;                            // BN floats
  int*      rp      = (int*)(sqv + BN);              // NRSLOT*BN (1 MB)
  int*      rn      = rp + (size_t)NRSLOT * BN;      // NRSLOT*BN (1 MB)
  int*      cp      = rn + (size_t)NRSLOT * BN;      // NRB*BN (2 MB)
  int*      cn      = cp + (size_t)NRB * BN;         // NRB*BN (2 MB)
  float*    blk_sum = (float*)(cn + (size_t)NRB * BN);   // 64
  float*    blk_cnt = blk_sum + 64;                  // 64
  unsigned* LP      = (unsigned*)(blk_cnt + 64);     // 2048 u32 (8 KB)
  char*     EnQ     = (char*)(LP + 2048);            // BN*DIM i8, k-major (~1 MB)

  norm_cvt_k<<<dim3(BN / 4), 256, 0, stream>>>(emb, lab, sqv, (unsigned short*)EnQ, LP);
  tri_strip_mine_k<<<dim3(NPAIR, NCHUNK), 256, 0, stream>>>(EnQ, lab, LP, rp, rn, cp, cn);
  finalize_a_k<<<dim3(NRB), 256, 0, stream>>>(rp, rn, cp, cn, sqv, blk_sum, blk_cnt);
  finalize_b_k<<<dim3(1), 64, 0, stream>>>(blk_sum, blk_cnt, out);
}

// Round 14
// 33.534 us; speedup vs baseline: 1.4017x; 1.4017x over previous
//
#include <hip/hip_runtime.h>
#include <cmath>

#define BN 8192
#define DIM 128
#define MARGIN_F 0.3f
#define NSPLIT 8            // column splits (1024 cols each)
#define CPS 1024
#define NT 8                // 128-col B tiles per panel
#define NPART (NSPLIT * 2)  // per-row partials: split x wc
#define FBLK 32
#define IMAX 0x7FFFFFFF
#define IMIN 0x80000000

typedef __attribute__((ext_vector_type(4))) int i32x4;

__device__ __forceinline__ int imin3(int a, int b, int c) { return min(a, min(b, c)); }
__device__ __forceinline__ int imax3(int a, int b, int c) { return max(a, max(b, c)); }

// ---------------- K1: fp32 row norms -> sqv + k-major i8 quantized copy ----------------
// Also LP: packed column-label table (LP[cb*16+lrow] = 4 label bytes of cols
// cb*64 + {0,16,32,48} + lrow; 128 groups, 8 KB, L2-resident), and zero-init of
// the K3 global accumulators (stream order makes them visible to K3).
__global__ __launch_bounds__(256) void norm_cvt_k(
    const float* __restrict__ emb, const int* __restrict__ lab,
    float* __restrict__ sqv, unsigned short* __restrict__ EnQ16,
    unsigned* __restrict__ LP, float* __restrict__ gacc /* [0]=sum [1]=cnt [2]=ctr */)
{
  int gt = blockIdx.x * blockDim.x + threadIdx.x;
  if (gt < 3) gacc[gt] = 0.f;   // gsum, gcnt, (int)gctr == 0.f bit pattern 0
  if (gt < 2048) {
    int base = (gt >> 4) * 64 + (gt & 15);
    LP[gt] = (unsigned)(lab[base] & 255) | ((unsigned)(lab[base + 16] & 255) << 8) |
             ((unsigned)(lab[base + 32] & 255) << 16) | ((unsigned)(lab[base + 48] & 255) << 24);
  }

  int w = gt >> 6;  // one wave per row
  int lane = threadIdx.x & 63;
  if (w >= BN) return;
  float2 v = *reinterpret_cast<const float2*>(&emb[w * DIM + lane * 2]);
  float s = v.x * v.x + v.y * v.y;
  #pragma unroll
  for (int off = 32; off > 0; off >>= 1) s += __shfl_xor(s, off);
  float iv = 1.0f / fmaxf(sqrtf(s), 1e-12f);
  if (lane == 0) sqv[w] = s * iv * iv;
  int q0 = (int)rintf(127.0f * v.x * iv);
  int q1 = (int)rintf(127.0f * v.y * iv);
  unsigned short us = (unsigned short)((q0 & 255) | ((q1 & 255) << 8));
  int g = lane >> 3;                                  // k = 2*lane -> chunk g = lane/8
  EnQ16[(g * BN + w) * 8 + (lane & 7)] = us;
}

// ---------------- K2: barrier-free i8-MFMA gram + hard mining (r8, proven 33.26) ----------------
// EnQ is 1 MB = L2-resident: B-frags read directly from global (L1/L2 hits, 4x256B
// contiguous per wave-load), no LDS, no barriers; waves run free. Half-deep pipeline:
// mine previous half under current half's MFMA+loads. LP gives column labels as one
// u32 per tile. Partials per (split, wc) slot — deterministic, no atomics.
__global__ __launch_bounds__(256, 2) void gram_mine_mfma_k(
    const char* __restrict__ EnQ, const int* __restrict__ lab,
    const unsigned* __restrict__ LP,
    int* __restrict__ ap_part, int* __restrict__ an_part)
{
  const int tid = threadIdx.x;
  const int w = tid >> 6, l = tid & 63;
  const int wr = w >> 1, wc = w & 1;
  const int lrow = l & 15, lkg = l >> 4;

  const int rowBase = blockIdx.x * 128 + wr * 64;   // this wave's 64 rows
  const int panel   = blockIdx.y * CPS;

  // A fragments: 4 row-tiles x 2 K-steps (K=64 each), 16B per frag, coalesced
  i32x4 a[4][2];
  #pragma unroll
  for (int mi = 0; mi < 4; ++mi)
    #pragma unroll
    for (int kk = 0; kk < 2; ++kk)
      a[mi][kk] = *reinterpret_cast<const i32x4*>(
          EnQ + (((size_t)((kk << 2) + lkg) * BN + rowBase + mi * 16 + lrow) << 4));

  // row labels for the 16 rows this lane owns, pre-extracted (tile-invariant)
  int rlv[4][4];
  #pragma unroll
  for (int mi = 0; mi < 4; ++mi) {
    int rb = rowBase + mi * 16 + lkg * 4;
    #pragma unroll
    for (int r = 0; r < 4; ++r) rlv[mi][r] = lab[rb + r] & 255;
  }

  int ap[4][4], an[4][4];
  #pragma unroll
  for (int mi = 0; mi < 4; ++mi)
    #pragma unroll
    for (int r = 0; r < 4; ++r) { ap[mi][r] = IMAX; an[mi][r] = IMIN; }

  const i32x4 zf = {0, 0, 0, 0};   // shared zero C-operand

  // B pointers: two bases (kk=0,1), advanced 2048 B per 128-col tile
  const int colLane = wc * 64 + lrow;
  const char* bp0 = EnQ + (((size_t)lkg * BN + panel + colLane) << 4);
  const char* bp1 = bp0 + ((size_t)BN << 6);   // += 4*BN*16

  auto loadHalf = [&](i32x4 (&b)[2][2], const char* p0, const char* p1, int n0) {
    #pragma unroll
    for (int n = 0; n < 2; ++n) {
      b[0][n] = *reinterpret_cast<const i32x4*>(p0 + (n0 + n) * 256);
      b[1][n] = *reinterpret_cast<const i32x4*>(p1 + (n0 + n) * 256);
    }
  };
  auto mfmaHalf = [&](i32x4 (&A)[4][2], const i32x4 (&b)[2][2]) {
    #pragma unroll
    for (int mi = 0; mi < 4; ++mi)
      #pragma unroll
      for (int n = 0; n < 2; ++n)
        A[mi][n] = __builtin_amdgcn_mfma_i32_16x16x64_i8(a[mi][0], b[0][n], zf, 0, 0, 0);
    #pragma unroll
    for (int mi = 0; mi < 4; ++mi)
      #pragma unroll
      for (int n = 0; n < 2; ++n)
        A[mi][n] = __builtin_amdgcn_mfma_i32_16x16x64_i8(a[mi][1], b[1][n], A[mi][n], 0, 0, 0);
  };

  // mine one 64x32 half: l0/l1 = column labels of the two 16-col subtiles (per-lane),
  // c0/c1 = local column index of this lane in those subtiles (self-exclusion on diag)
  auto mineTile = [&](const i32x4 (&A)[4][2], int l0, int l1, int c0, int c1, bool dg) {
    if (!dg) {
      #pragma unroll
      for (int mi = 0; mi < 4; ++mi)
        #pragma unroll
        for (int r = 0; r < 4; ++r) {
          int d0 = A[mi][0][r], d1 = A[mi][1][r];
          bool s0 = (rlv[mi][r] == l0), s1 = (rlv[mi][r] == l1);
          int p0 = s0 ? d0 : IMAX;
          int p1 = s1 ? d1 : IMAX;
          int q0 = s0 ? IMIN : d0;
          int q1 = s1 ? IMIN : d1;
          ap[mi][r] = imin3(ap[mi][r], p0, p1);
          an[mi][r] = imax3(an[mi][r], q0, q1);
        }
    } else {
      #pragma unroll
      for (int mi = 0; mi < 4; ++mi)
        #pragma unroll
        for (int r = 0; r < 4; ++r) {
          int rloc = mi * 16 + lkg * 4 + r;
          int d0 = A[mi][0][r], d1 = A[mi][1][r];
          bool s0 = (rlv[mi][r] == l0), s1 = (rlv[mi][r] == l1);
          bool e0 = (rloc == c0), e1 = (rloc == c1);
          int p0 = (s0 && !e0) ? d0 : IMAX;
          int p1 = (s1 && !e1) ? d1 : IMAX;
          int q0 = s0 ? IMIN : d0;
          int q1 = s1 ? IMIN : d1;
          ap[mi][r] = imin3(ap[mi][r], p0, p1);
          an[mi][r] = imax3(an[mi][r], q0, q1);
        }
    }
  };

  i32x4 accA[4][2], accB[4][2];
  i32x4 bA[2][2], bB[2][2];
  int lprev0 = 0, lprev1 = 0;
  bool diagP = false;

  loadHalf(bA, bp0, bp1, 0);   // tile 0, half 0

  #pragma unroll 1
  for (int ct = 0; ct < NT; ++ct) {
    const int colBase = panel + ct * 128 + wc * 64;
    const bool diag = (rowBase == colBase);

    // packed column labels for this wave's 64 cols: one u32
    const unsigned LPv = LP[(colBase >> 6) * 16 + lrow];
    const int l0 = (int)(LPv & 255u),         l1 = (int)((LPv >> 8) & 255u);
    const int l2 = (int)((LPv >> 16) & 255u), l3 = (int)(LPv >> 24);

    loadHalf(bB, bp0, bp1, 2);           // this tile, half 1 (in flight)
    mfmaHalf(accA, bA);                  // half 0 MFMA (waits on bA)
    if (ct > 0) mineTile(accB, lprev0, lprev1, 32 + lrow, 48 + lrow, diagP);  // prev half 1

    bp0 += 2048; bp1 += 2048;
    if (ct + 1 < NT) loadHalf(bA, bp0, bp1, 0);   // next tile, half 0 (in flight)

    mfmaHalf(accB, bB);                  // half 1 MFMA
    mineTile(accA, l0, l1, 0 + lrow, 16 + lrow, diag);   // this half 0

    lprev0 = l2; lprev1 = l3; diagP = diag;
  }
  // drain: last tile's half 1
  mineTile(accB, lprev0, lprev1, 32 + lrow, 48 + lrow, diagP);

  // butterfly-reduce across the 16 lrow lanes sharing each C row, write partials
  const int part = blockIdx.y * 2 + wc;
  #pragma unroll
  for (int mi = 0; mi < 4; ++mi)
    #pragma unroll
    for (int r = 0; r < 4; ++r) {
      int p = ap[mi][r], n = an[mi][r];
      #pragma unroll
      for (int off = 1; off < 16; off <<= 1) {
        p = min(p, __shfl_xor(p, off));
        n = max(n, __shfl_xor(n, off));
      }
      if (lrow == 0) {
        int rg = rowBase + mi * 16 + lkg * 4 + r;
        ap_part[part * BN + rg] = p;
        an_part[part * BN + rg] = n;
      }
    }
}

// ---------------- K3: per-row combine + fused final scalar ----------------
// 32 blocks as before; each block atomically adds its (sum, cnt) into gacc and
// the counter-elected last block computes out. Atomics only (no hot-data fences —
// the r1 poison was fences inside the 47us gram kernel; 32 fences in this tiny
// epilogue are free). Float add order nondeterministic -> out varies ~1e-8: fine.
__global__ __launch_bounds__(256) void finalize_k(
    const int* __restrict__ ap_part, const int* __restrict__ an_part,
    const float* __restrict__ sqv,
    float* __restrict__ gacc /* [0]=sum [1]=cnt [2]=ctr(int) */,
    float* __restrict__ out)
{
  int r = blockIdx.x * 256 + threadIdx.x;   // FBLK*256 == BN
  int apt = IMAX, ant = IMIN;               // min-idot pos / max-idot neg
  #pragma unroll 8
  for (int s = 0; s < NPART; ++s) {
    apt = min(apt, ap_part[s * BN + r]);
    ant = max(ant, an_part[s * BN + r]);
  }
  float sum = 0.f, cnt = 0.f;
  if (apt != IMAX && ant != IMIN) {
    const float sc = 2.0f / (127.0f * 127.0f);
    float rs1 = sqv[r] + 1.0f;
    float dap = sqrtf(fmaxf(fmaf(-sc, (float)apt, rs1), 0.f));
    float dan = sqrtf(fmaxf(fmaf(-sc, (float)ant, rs1), 0.f));
    sum = fmaxf(dap - dan + MARGIN_F, 0.f);
    cnt = 1.f;
  }
  #pragma unroll
  for (int off = 32; off > 0; off >>= 1) {
    sum += __shfl_xor(sum, off);
    cnt += __shfl_xor(cnt, off);
  }
  __shared__ float ssum[4], scnt[4];
  int wv = threadIdx.x >> 6;
  if ((threadIdx.x & 63) == 0) { ssum[wv] = sum; scnt[wv] = cnt; }
  __syncthreads();
  if (threadIdx.x == 0) {
    float bs = ssum[0] + ssum[1] + ssum[2] + ssum[3];
    float bc = scnt[0] + scnt[1] + scnt[2] + scnt[3];
    atomicAdd(&gacc[0], bs);
    atomicAdd(&gacc[1], bc);
    __threadfence();   // order the adds before the counter (release)
    int old = atomicAdd((int*)&gacc[2], 1);
    if (old == FBLK - 1) {
      __threadfence();                         // acquire
      float s = atomicAdd(&gacc[0], 0.f);      // coherent atomic read
      float c = atomicAdd(&gacc[1], 0.f);
      out[0] = (c > 0.f) ? (s / c) : 0.f;
      gacc[0] = 0.f; gacc[1] = 0.f; *(int*)&gacc[2] = 0;   // replay-friendly reset
    }
  }
}

extern "C" void kernel_launch(void* const* d_in, const int* in_sizes, int n_in,
                              void* d_out, int out_size, void* d_ws, size_t ws_size,
                              hipStream_t stream)
{
  const float* emb = (const float*)d_in[0];
  const int*   lab = (const int*)d_in[1];
  float* out = (float*)d_out;
  float* ws  = (float*)d_ws;

  float*    sqv     = ws;                          // BN floats
  int*      ap_part = (int*)(sqv + BN);            // NPART*BN ints
  int*      an_part = ap_part + NPART * BN;        // NPART*BN ints
  unsigned* LP      = (unsigned*)(an_part + NPART * BN);  // 2048 u32 (8 KB)
  float*    gacc    = (float*)(LP + 2048);         // gsum, gcnt, gctr
  char*     EnQ     = (char*)(gacc + 16);          // BN*DIM i8, k-major (~1 MB)

  norm_cvt_k<<<dim3(BN / 4), 256, 0, stream>>>(emb, lab, sqv, (unsigned short*)EnQ, LP, gacc);
  gram_mine_mfma_k<<<dim3(BN / 128, NSPLIT), 256, 0, stream>>>(EnQ, lab, LP, ap_part, an_part);
  finalize_k<<<dim3(FBLK), 256, 0, stream>>>(ap_part, an_part, sqv, gacc, out);
}